// Round 2
// baseline (229.249 us; speedup 1.0000x reference)
//
#include <hip/hip_runtime.h>

#define S_LEN 2048
#define D_DIM 64
#define BH 32
#define NN ((size_t)BH * S_LEN * D_DIM)  // 4,194,304 elems per ws buffer

typedef short bf16x8 __attribute__((ext_vector_type(8)));
typedef float f32x4 __attribute__((ext_vector_type(4)));

static __device__ __forceinline__ unsigned short f2bf(float x) {
  unsigned int u = __float_as_uint(x);
  u += 0x7fffu + ((u >> 16) & 1u);
  return (unsigned short)(u >> 16);
}
static __device__ __forceinline__ float bf2f(unsigned short h) {
  return __uint_as_float(((unsigned int)h) << 16);
}

// 64x64 tile transpose with fp32 -> bf16 hi/lo split.
// in: [BH][R][C] fp32 ; outh/outl: [BH][C][R] bf16 bit patterns
__global__ void transpose_split(const float* __restrict__ in,
                                unsigned short* __restrict__ outh,
                                unsigned short* __restrict__ outl,
                                int R, int C) {
  __shared__ float tile[64][65];
  int bh = blockIdx.y;
  int tilesPerRow = C >> 6;
  int tr = blockIdx.x / tilesPerRow;
  int tc = blockIdx.x % tilesPerRow;
  int tid = threadIdx.x;
  int cc = tid & 63, r4 = tid >> 6;
  const float* src = in + (size_t)bh * R * C;
#pragma unroll
  for (int rep = 0; rep < 16; ++rep) {
    int r = rep * 4 + r4;
    tile[r][cc] = src[(size_t)(tr * 64 + r) * C + tc * 64 + cc];
  }
  __syncthreads();
  unsigned short* oh = outh + (size_t)bh * R * C;
  unsigned short* ol = outl + (size_t)bh * R * C;
#pragma unroll
  for (int rep = 0; rep < 16; ++rep) {
    int c = rep * 4 + r4;
    float x = tile[cc][c];
    unsigned short hb = f2bf(x);
    unsigned short lb = f2bf(x - bf2f(hb));
    size_t o = (size_t)(tc * 64 + c) * R + tr * 64 + cc;
    oh[o] = hb;
    ol[o] = lb;
  }
}

// Fused exp-attention. Block = 256 thr (4 waves), QTILE=128 (32 q-rows/wave),
// KT=64 keys/iter. 16x16x32 bf16 MFMA, hi/lo split for near-fp32 accuracy.
// K/V fragments hoisted to registers (shared across both 16-row blocks);
// P stored packed (hi|lo<<16) in LDS so PV A-frags need no re-conversion.
__global__ __launch_bounds__(256, 2) void attn_fused(
    const float* __restrict__ q, const unsigned short* __restrict__ Khg,
    const unsigned short* __restrict__ Klg, const unsigned short* __restrict__ Vhg,
    const unsigned short* __restrict__ Vlg, float* __restrict__ out) {
  __shared__ __align__(16) unsigned short KhT[64][72];  // [t][d], 144B rows
  __shared__ __align__(16) unsigned short KlT[64][72];
  __shared__ __align__(16) unsigned short VhT[64][72];  // [d][t]
  __shared__ __align__(16) unsigned short VlT[64][72];
  __shared__ __align__(16) unsigned int Pb[4][32][68];  // per-wave packed P

  const int bh = blockIdx.x >> 4;
  const int qt = blockIdx.x & 15;
  const int tid = threadIdx.x;
  const int w = tid >> 6;
  const int lane = tid & 63;
  const int lg = lane >> 4;  // 16-lane group 0..3
  const int ln = lane & 15;

  // ---- Q fragments, held in registers for the whole kernel ----
  // A-frag (16x16x32): row = ln, k = c*32 + lg*8 + j
  bf16x8 qh[2][2], ql[2][2];
  {
    const float* qb = q + ((size_t)bh * S_LEN + qt * 128 + w * 32) * D_DIM;
#pragma unroll
    for (int rb = 0; rb < 2; ++rb)
#pragma unroll
      for (int c = 0; c < 2; ++c) {
        const float* p = qb + (size_t)(rb * 16 + ln) * D_DIM + c * 32 + lg * 8;
        float4 x0 = *(const float4*)p;
        float4 x1 = *(const float4*)(p + 4);
        float xs[8] = {x0.x, x0.y, x0.z, x0.w, x1.x, x1.y, x1.z, x1.w};
        bf16x8 hh, ll;
#pragma unroll
        for (int j = 0; j < 8; ++j) {
          unsigned short hb = f2bf(xs[j]);
          hh[j] = (short)hb;
          ll[j] = (short)f2bf(xs[j] - bf2f(hb));
        }
        qh[rb][c] = hh;
        ql[rb][c] = ll;
      }
  }

  f32x4 o[2][4] = {};
  float lsum[2][4] = {};

  for (int kt = 0; kt < S_LEN / 64; ++kt) {
    __syncthreads();  // previous tiles fully consumed
    {
      const int bt = kt * 64;
#pragma unroll
      for (int rep = 0; rep < 2; ++rep) {
        int idx = rep * 256 + tid;
        int row = idx >> 3;
        int ch = (idx & 7) << 3;
        size_t gk = ((size_t)bh * S_LEN + bt + row) * D_DIM + ch;   // Kt[bh][t][d]
        size_t gv = ((size_t)bh * D_DIM + row) * S_LEN + bt + ch;   // Vt[bh][d][t]
        *(int4*)&KhT[row][ch] = *(const int4*)(Khg + gk);
        *(int4*)&KlT[row][ch] = *(const int4*)(Klg + gk);
        *(int4*)&VhT[row][ch] = *(const int4*)(Vhg + gv);
        *(int4*)&VlT[row][ch] = *(const int4*)(Vlg + gv);
      }
    }
    __syncthreads();

    // ---- hoisted K fragments (B-frag: col=t=ln, k = c*32+lg*8+j) ----
    bf16x8 kh[4][2], kl[4][2];
#pragma unroll
    for (int sub = 0; sub < 4; ++sub)
#pragma unroll
      for (int c = 0; c < 2; ++c) {
        kh[sub][c] = *(const bf16x8*)&KhT[sub * 16 + ln][c * 32 + lg * 8];
        kl[sub][c] = *(const bf16x8*)&KlT[sub * 16 + ln][c * 32 + lg * 8];
      }

    // ---- S = Q·Kt, exp, pack P to LDS ----
#pragma unroll
    for (int rb = 0; rb < 2; ++rb) {
#pragma unroll
      for (int sub = 0; sub < 4; ++sub) {
        f32x4 acc = {0.f, 0.f, 0.f, 0.f};
#pragma unroll
        for (int c = 0; c < 2; ++c) {
          acc = __builtin_amdgcn_mfma_f32_16x16x32_bf16(qh[rb][c], kh[sub][c], acc, 0, 0, 0);
          acc = __builtin_amdgcn_mfma_f32_16x16x32_bf16(qh[rb][c], kl[sub][c], acc, 0, 0, 0);
          acc = __builtin_amdgcn_mfma_f32_16x16x32_bf16(ql[rb][c], kh[sub][c], acc, 0, 0, 0);
        }
        // C/D layout: row = lg*4+i, col = ln  (measured m89/m91)
#pragma unroll
        for (int i = 0; i < 4; ++i) {
          float pv = exp2f(acc[i] * 0.18033688011112042f);  // exp(acc/8)
          lsum[rb][i] += pv;
          unsigned short hb = f2bf(pv);
          unsigned short lb = f2bf(pv - bf2f(hb));
          Pb[w][rb * 16 + lg * 4 + i][sub * 16 + ln] =
              (unsigned int)hb | ((unsigned int)lb << 16);
        }
      }
    }

    // ---- hoisted V fragments (B-frag: col=d=ln, k(t) = cc*32+lg*8+j) ----
    bf16x8 vh[4][2], vl[4][2];
#pragma unroll
    for (int dsub = 0; dsub < 4; ++dsub)
#pragma unroll
      for (int cc = 0; cc < 2; ++cc) {
        vh[dsub][cc] = *(const bf16x8*)&VhT[dsub * 16 + ln][cc * 32 + lg * 8];
        vl[dsub][cc] = *(const bf16x8*)&VlT[dsub * 16 + ln][cc * 32 + lg * 8];
      }

    asm volatile("s_waitcnt lgkmcnt(0)" ::: "memory");  // P writes visible wave-wide

    // ---- O += P·V ----
#pragma unroll
    for (int rb = 0; rb < 2; ++rb) {
      // P A-frag: row = ln, t = cc*32 + lg*8 + j ; unpack hi/lo from packed u32
      bf16x8 ph[2], pl[2];
#pragma unroll
      for (int cc = 0; cc < 2; ++cc) {
        const unsigned int* pp = &Pb[w][rb * 16 + ln][cc * 32 + lg * 8];
        uint4 ra = *(const uint4*)pp;
        uint4 rc = *(const uint4*)(pp + 4);
        unsigned int r[8] = {ra.x, ra.y, ra.z, ra.w, rc.x, rc.y, rc.z, rc.w};
        uint4 hv, lv;
        hv.x = (r[0] & 0xffffu) | (r[1] << 16);
        lv.x = (r[0] >> 16) | (r[1] & 0xffff0000u);
        hv.y = (r[2] & 0xffffu) | (r[3] << 16);
        lv.y = (r[2] >> 16) | (r[3] & 0xffff0000u);
        hv.z = (r[4] & 0xffffu) | (r[5] << 16);
        lv.z = (r[4] >> 16) | (r[5] & 0xffff0000u);
        hv.w = (r[6] & 0xffffu) | (r[7] << 16);
        lv.w = (r[6] >> 16) | (r[7] & 0xffff0000u);
        ph[cc] = __builtin_bit_cast(bf16x8, hv);
        pl[cc] = __builtin_bit_cast(bf16x8, lv);
      }
#pragma unroll
      for (int dsub = 0; dsub < 4; ++dsub)
#pragma unroll
        for (int cc = 0; cc < 2; ++cc) {
          o[rb][dsub] = __builtin_amdgcn_mfma_f32_16x16x32_bf16(ph[cc], vh[dsub][cc], o[rb][dsub], 0, 0, 0);
          o[rb][dsub] = __builtin_amdgcn_mfma_f32_16x16x32_bf16(ph[cc], vl[dsub][cc], o[rb][dsub], 0, 0, 0);
          o[rb][dsub] = __builtin_amdgcn_mfma_f32_16x16x32_bf16(pl[cc], vh[dsub][cc], o[rb][dsub], 0, 0, 0);
        }
    }
  }

  // ---- epilogue: reduce l across the 16 lanes of each row-group, store ----
#pragma unroll
  for (int rb = 0; rb < 2; ++rb) {
    float ls[4];
#pragma unroll
    for (int i = 0; i < 4; ++i) {
      float v = lsum[rb][i];
      v += __shfl_xor(v, 1);
      v += __shfl_xor(v, 2);
      v += __shfl_xor(v, 4);
      v += __shfl_xor(v, 8);
      ls[i] = v;
    }
#pragma unroll
    for (int dsub = 0; dsub < 4; ++dsub)
#pragma unroll
      for (int i = 0; i < 4; ++i) {
        int row = qt * 128 + w * 32 + rb * 16 + lg * 4 + i;
        out[((size_t)bh * S_LEN + row) * D_DIM + dsub * 16 + ln] =
            o[rb][dsub][i] / ls[i];
      }
  }
}

extern "C" void kernel_launch(void* const* d_in, const int* in_sizes, int n_in,
                              void* d_out, int out_size, void* d_ws, size_t ws_size,
                              hipStream_t stream) {
  const float* q = (const float*)d_in[0];
  const float* k = (const float*)d_in[1];  // [bh][d][s] (pre-transposed)
  const float* v = (const float*)d_in[2];  // [bh][s][d]
  float* out = (float*)d_out;
  unsigned short* ws = (unsigned short*)d_ws;
  unsigned short* Kh = ws;
  unsigned short* Kl = ws + NN;
  unsigned short* Vh = ws + 2 * NN;
  unsigned short* Vl = ws + 3 * NN;
  // K: [bh][64][2048] -> Kt [bh][2048][64] (hi/lo bf16)
  transpose_split<<<dim3(32, BH), 256, 0, stream>>>(k, Kh, Kl, 64, 2048);
  // V: [bh][2048][64] -> Vt [bh][64][2048] (hi/lo bf16)
  transpose_split<<<dim3(32, BH), 256, 0, stream>>>(v, Vh, Vl, 2048, 64);
  attn_fused<<<dim3(512), 256, 0, stream>>>(q, Kh, Kl, Vh, Vl, out);
}

// Round 3
// 189.973 us; speedup vs baseline: 1.2067x; 1.2067x over previous
//
#include <hip/hip_runtime.h>

#define S_LEN 2048
#define D_DIM 64
#define BH 32
#define NN ((size_t)BH * S_LEN * D_DIM)  // elems per ws buffer

typedef short bf16x8 __attribute__((ext_vector_type(8)));
typedef float f32x16 __attribute__((ext_vector_type(16)));
typedef unsigned int u32x4 __attribute__((ext_vector_type(4)));

static __device__ __forceinline__ unsigned short f2bf(float x) {
  unsigned int u = __float_as_uint(x);
  u += 0x7fffu + ((u >> 16) & 1u);
  return (unsigned short)(u >> 16);
}
static __device__ __forceinline__ float bf2f(unsigned short h) {
  return __uint_as_float(((unsigned int)h) << 16);
}
static __device__ __forceinline__ void gll16(const void* g, void* l) {
  __builtin_amdgcn_global_load_lds((const __attribute__((address_space(1))) void*)g,
                                   (__attribute__((address_space(3))) void*)l, 16, 0, 0);
}

// 64x64 tile transpose + fp32 -> bf16 hi/lo split. in:[BH][R][C] -> out:[BH][C][R].
// PERM: bit2<->bit3 swap of the output-column index within each 16-group
// (pre-permutes V's key axis to match the PV A-fragment register order).
template <bool PERM>
__global__ void transpose_split(const float* __restrict__ in,
                                unsigned short* __restrict__ outh,
                                unsigned short* __restrict__ outl,
                                int R, int C) {
  __shared__ float tile[64][65];
  const int bh = blockIdx.y;
  const int tilesPerRow = C >> 6;
  const int tr = blockIdx.x / tilesPerRow;
  const int tc = blockIdx.x % tilesPerRow;
  const int tid = threadIdx.x;
  const float* src = in + (size_t)bh * R * C;
  {
    const int c4 = (tid & 15) * 4;
    const int r0 = tid >> 4;
#pragma unroll
    for (int rep = 0; rep < 4; ++rep) {
      int r = r0 + rep * 16;
      float4 x = *(const float4*)&src[(size_t)(tr * 64 + r) * C + tc * 64 + c4];
      tile[r][c4] = x.x; tile[r][c4 + 1] = x.y; tile[r][c4 + 2] = x.z; tile[r][c4 + 3] = x.w;
    }
  }
  __syncthreads();
  unsigned short* oh = outh + (size_t)bh * R * C;
  unsigned short* ol = outl + (size_t)bh * R * C;
#pragma unroll
  for (int rep = 0; rep < 2; ++rep) {
    int ci = rep * 256 + tid;
    int orow = ci >> 3;
    int oslot = ci & 7;
    alignas(16) unsigned short hbuf[8];
    alignas(16) unsigned short lbuf[8];
#pragma unroll
    for (int i = 0; i < 8; ++i) {
      int p = oslot * 8 + i;
      int ridx = PERM ? ((p & ~15) | (p & 3) | ((p & 4) << 1) | ((p & 8) >> 1)) : p;
      float x = tile[ridx][orow];
      unsigned short hb = f2bf(x);
      hbuf[i] = hb;
      lbuf[i] = f2bf(x - bf2f(hb));
    }
    size_t o = (size_t)(tc * 64 + orow) * R + tr * 64 + oslot * 8;
    *(int4*)&oh[o] = *(const int4*)hbuf;
    *(int4*)&ol[o] = *(const int4*)lbuf;
  }
}

// Fused exp-attention, swapped-QK^T 32x32x16 MFMA, in-register P, hi/lo bf16 QK.
// 256 thr (4 waves), QTILE=128 (32 q-rows/wave), 64 keys/iter, dbuf LDS via
// global_load_lds (XOR-swizzled 16B chunks), 1 barrier/iter.
__global__ __launch_bounds__(256, 2) void attn_fused(
    const float* __restrict__ q, const unsigned short* __restrict__ Khg,
    const unsigned short* __restrict__ Klg, const unsigned short* __restrict__ Vhg,
    const unsigned short* __restrict__ Vlg, float* __restrict__ out) {
  __shared__ __align__(16) unsigned short smem[2][4][64][64];  // [buf][Kh,Kl,Vh,Vl][row][col]
  __shared__ float Lrow[4][32];

  const int bid = blockIdx.x;
  const int swz = (bid & 7) * 64 + (bid >> 3);  // XCD-contiguous: 4 heads per XCD
  const int bh = swz >> 4;
  const int qt = swz & 15;
  const int tid = threadIdx.x;
  const int w = tid >> 6;
  const int lane = tid & 63;
  const int l31 = lane & 31;
  const int h = lane >> 5;
  const int q0 = qt * 128 + w * 32;

  // ---- Q B-fragments in registers: col(qrow)=l31, k(d)=ks*16+h*8+j ----
  bf16x8 qh[4], ql[4];
  {
    const float* qb = q + ((size_t)bh * S_LEN + q0 + l31) * D_DIM;
#pragma unroll
    for (int ks = 0; ks < 4; ++ks) {
      const float* p = qb + ks * 16 + h * 8;
      float4 x0 = *(const float4*)p;
      float4 x1 = *(const float4*)(p + 4);
      float xs[8] = {x0.x, x0.y, x0.z, x0.w, x1.x, x1.y, x1.z, x1.w};
      bf16x8 hh, ll;
#pragma unroll
      for (int j = 0; j < 8; ++j) {
        unsigned short hb = f2bf(xs[j]);
        hh[j] = (short)hb;
        ll[j] = (short)f2bf(xs[j] - bf2f(hb));
      }
      qh[ks] = hh; ql[ks] = ll;
    }
  }

  // staging geometry: chunk c=(r*4+w)*64+lane; row=c>>3; lslot=c&7; gslot=lslot^(row&7)
  int rowA[2], gsA[2];
#pragma unroll
  for (int r = 0; r < 2; ++r) {
    int c = (r * 4 + w) * 64 + lane;
    rowA[r] = c >> 3;
    gsA[r] = (c & 7) ^ ((c >> 3) & 7);
  }
  const unsigned short* Kh_b = Khg + (size_t)bh * S_LEN * D_DIM;
  const unsigned short* Kl_b = Klg + (size_t)bh * S_LEN * D_DIM;
  const unsigned short* Vh_b = Vhg + (size_t)bh * D_DIM * S_LEN;
  const unsigned short* Vl_b = Vlg + (size_t)bh * D_DIM * S_LEN;

  auto stage = [&](int buf, int bt) {
#pragma unroll
    for (int r = 0; r < 2; ++r) {
      const int row = rowA[r], gs = gsA[r];
      unsigned short* lbase = &smem[buf][0][0][0] + (r * 4 + w) * 512;  // wave-uniform
      gll16(Kh_b + (size_t)(bt + row) * 64 + gs * 8, lbase);
      gll16(Kl_b + (size_t)(bt + row) * 64 + gs * 8, lbase + 4096);
      gll16(Vh_b + (size_t)row * S_LEN + bt + gs * 8, lbase + 8192);
      gll16(Vl_b + (size_t)row * S_LEN + bt + gs * 8, lbase + 12288);
    }
  };

  f32x16 o[2] = {};
  float lsum = 0.f;
  const int kx = l31 & 7;

  stage(0, 0);
  __syncthreads();

  int cur = 0;
  for (int kt = 0; kt < 32; ++kt) {
    if (kt < 31) stage(cur ^ 1, (kt + 1) * 64);

    bf16x8 pa[4];
#pragma unroll
    for (int kt2 = 0; kt2 < 2; ++kt2) {
      f32x16 acc = {};
      const int krow = kt2 * 32 + l31;
#pragma unroll
      for (int ks = 0; ks < 4; ++ks) {
        const int sl = ((ks * 2 + h) ^ kx) * 8;
        bf16x8 kh = *(const bf16x8*)&smem[cur][0][krow][sl];
        bf16x8 kl = *(const bf16x8*)&smem[cur][1][krow][sl];
        acc = __builtin_amdgcn_mfma_f32_32x32x16_bf16(kh, qh[ks], acc, 0, 0, 0);
        acc = __builtin_amdgcn_mfma_f32_32x32x16_bf16(kh, ql[ks], acc, 0, 0, 0);
        acc = __builtin_amdgcn_mfma_f32_32x32x16_bf16(kl, qh[ks], acc, 0, 0, 0);
      }
      float pr[16];
#pragma unroll
      for (int i = 0; i < 16; ++i) {
        pr[i] = exp2f(acc[i] * 0.18033688011112042f);  // exp(acc/8)
        lsum += pr[i];
      }
      // A-frag = regs in order (V key-axis pre-permuted in transpose): pack pairs
#pragma unroll
      for (int s2 = 0; s2 < 2; ++s2) {
        u32x4 wds;
#pragma unroll
        for (int p2 = 0; p2 < 4; ++p2) {
          wds[p2] = (unsigned int)f2bf(pr[s2 * 8 + p2 * 2]) |
                    ((unsigned int)f2bf(pr[s2 * 8 + p2 * 2 + 1]) << 16);
        }
        pa[kt2 * 2 + s2] = __builtin_bit_cast(bf16x8, wds);
      }
    }

#pragma unroll
    for (int s = 0; s < 4; ++s) {
#pragma unroll
      for (int db = 0; db < 2; ++db) {
        const int vrow = db * 32 + l31;
        const int sl = ((s * 2 + h) ^ kx) * 8;
        bf16x8 vh = *(const bf16x8*)&smem[cur][2][vrow][sl];
        bf16x8 vl = *(const bf16x8*)&smem[cur][3][vrow][sl];
        o[db] = __builtin_amdgcn_mfma_f32_32x32x16_bf16(pa[s], vh, o[db], 0, 0, 0);
        o[db] = __builtin_amdgcn_mfma_f32_32x32x16_bf16(pa[s], vl, o[db], 0, 0, 0);
      }
    }

    __syncthreads();  // drains DMA (vmcnt) + all waves done with cur
    cur ^= 1;
  }

  // ---- epilogue: l = own-half + partner-half, broadcast 1/l per qrow via LDS ----
  float fl = lsum + __shfl_xor(lsum, 32);
  float inv = 1.0f / fl;
  Lrow[w][l31] = inv;  // both halves write identical value
  __syncthreads();
  float linv[16];
#pragma unroll
  for (int r = 0; r < 16; ++r) linv[r] = Lrow[w][(r & 3) + 8 * (r >> 2) + 4 * h];
  float* ob = out + ((size_t)bh * S_LEN + q0) * D_DIM;
#pragma unroll
  for (int db = 0; db < 2; ++db)
#pragma unroll
    for (int r = 0; r < 16; ++r) {
      const int qr = (r & 3) + 8 * (r >> 2) + 4 * h;
      ob[(size_t)qr * D_DIM + db * 32 + l31] = o[db][r] * linv[r];
    }
}

extern "C" void kernel_launch(void* const* d_in, const int* in_sizes, int n_in,
                              void* d_out, int out_size, void* d_ws, size_t ws_size,
                              hipStream_t stream) {
  const float* q = (const float*)d_in[0];
  const float* k = (const float*)d_in[1];  // [bh][d][s] (pre-transposed)
  const float* v = (const float*)d_in[2];  // [bh][s][d]
  float* out = (float*)d_out;
  unsigned short* ws = (unsigned short*)d_ws;
  unsigned short* Kh = ws;
  unsigned short* Kl = ws + NN;
  unsigned short* Vh = ws + 2 * NN;
  unsigned short* Vl = ws + 3 * NN;
  // K: [bh][64][2048] -> Kt [bh][2048][64] (straight)
  transpose_split<false><<<dim3(32, BH), 256, 0, stream>>>(k, Kh, Kl, 64, 2048);
  // V: [bh][2048][64] -> Vt [bh][64][2048] with key-axis bit2<->bit3 permutation
  transpose_split<true><<<dim3(32, BH), 256, 0, stream>>>(v, Vh, Vl, 2048, 64);
  attn_fused<<<dim3(512), 256, 0, stream>>>(q, Kh, Kl, Vh, Vl, out);
}

// Round 4
// 171.603 us; speedup vs baseline: 1.3359x; 1.1071x over previous
//
#include <hip/hip_runtime.h>

#define S_LEN 2048
#define D_DIM 64
#define BH 32
#define NN ((size_t)BH * S_LEN * D_DIM)  // elems per ws buffer

typedef short bf16x8 __attribute__((ext_vector_type(8)));
typedef float f32x16 __attribute__((ext_vector_type(16)));
typedef unsigned int u32x4 __attribute__((ext_vector_type(4)));

static __device__ __forceinline__ unsigned short f2bf(float x) {
  unsigned int u = __float_as_uint(x);
  u += 0x7fffu + ((u >> 16) & 1u);
  return (unsigned short)(u >> 16);
}
static __device__ __forceinline__ float bf2f(unsigned short h) {
  return __uint_as_float(((unsigned int)h) << 16);
}
static __device__ __forceinline__ void gll16(const void* g, void* l) {
  __builtin_amdgcn_global_load_lds((const __attribute__((address_space(1))) void*)g,
                                   (__attribute__((address_space(3))) void*)l, 16, 0, 0);
}

// 64x64 tile transpose + fp32 -> bf16 split. in:[BH][R][C] -> out:[BH][C][R].
// PERM: bit2<->bit3 swap of output-column index within each 16-group (pre-permutes
// V's key axis to match the PV A-fragment register order). LO: emit lo residual.
template <bool PERM, bool LO>
__global__ void transpose_split(const float* __restrict__ in,
                                unsigned short* __restrict__ outh,
                                unsigned short* __restrict__ outl,
                                int R, int C) {
  __shared__ float tile[64][65];
  const int bh = blockIdx.y;
  const int tilesPerRow = C >> 6;
  const int tr = blockIdx.x / tilesPerRow;
  const int tc = blockIdx.x % tilesPerRow;
  const int tid = threadIdx.x;
  const float* src = in + (size_t)bh * R * C;
  {
    const int c4 = (tid & 15) * 4;
    const int r0 = tid >> 4;
#pragma unroll
    for (int rep = 0; rep < 4; ++rep) {
      int r = r0 + rep * 16;
      float4 x = *(const float4*)&src[(size_t)(tr * 64 + r) * C + tc * 64 + c4];
      tile[r][c4] = x.x; tile[r][c4 + 1] = x.y; tile[r][c4 + 2] = x.z; tile[r][c4 + 3] = x.w;
    }
  }
  __syncthreads();
  unsigned short* oh = outh + (size_t)bh * R * C;
  unsigned short* ol = outl + (size_t)bh * R * C;
#pragma unroll
  for (int rep = 0; rep < 2; ++rep) {
    int ci = rep * 256 + tid;
    int orow = ci >> 3;
    int oslot = ci & 7;
    alignas(16) unsigned short hbuf[8];
    alignas(16) unsigned short lbuf[8];
#pragma unroll
    for (int i = 0; i < 8; ++i) {
      int p = oslot * 8 + i;
      int ridx = PERM ? ((p & ~15) | (p & 3) | ((p & 4) << 1) | ((p & 8) >> 1)) : p;
      float x = tile[ridx][orow];
      unsigned short hb = f2bf(x);
      hbuf[i] = hb;
      if (LO) lbuf[i] = f2bf(x - bf2f(hb));
    }
    size_t o = (size_t)(tc * 64 + orow) * R + tr * 64 + oslot * 8;
    *(int4*)&oh[o] = *(const int4*)hbuf;
    if (LO) *(int4*)&ol[o] = *(const int4*)lbuf;
  }
}

// Fused exp-attention, swapped-QK^T 32x32x16 MFMA, in-register P, hi/lo bf16 QK,
// single-bf16 V. 256 thr (4 waves), 32 q-rows/wave, 64 keys/iter, dbuf LDS via
// global_load_lds (XOR-swizzled 16B chunks), 1 barrier/iter.
__global__ __launch_bounds__(256, 2) void attn_fused(
    const float* __restrict__ q, const unsigned short* __restrict__ Khg,
    const unsigned short* __restrict__ Klg, const unsigned short* __restrict__ Vhg,
    float* __restrict__ out) {
  __shared__ __align__(16) unsigned short smem[2][3][64][64];  // [buf][Kh,Kl,Vh][row][col]
  __shared__ float Lrow[4][32];

  const int bid = blockIdx.x;
  const int swz = (bid & 7) * 64 + (bid >> 3);  // XCD-contiguous: 4 heads per XCD
  const int bh = swz >> 4;
  const int qt = swz & 15;
  const int tid = threadIdx.x;
  const int w = tid >> 6;
  const int lane = tid & 63;
  const int l31 = lane & 31;
  const int h = lane >> 5;
  const int q0 = qt * 128 + w * 32;

  // ---- Q B-fragments in registers: col(qrow)=l31, k(d)=ks*16+h*8+j ----
  bf16x8 qh[4], ql[4];
  {
    const float* qb = q + ((size_t)bh * S_LEN + q0 + l31) * D_DIM;
#pragma unroll
    for (int ks = 0; ks < 4; ++ks) {
      const float* p = qb + ks * 16 + h * 8;
      float4 x0 = *(const float4*)p;
      float4 x1 = *(const float4*)(p + 4);
      float xs[8] = {x0.x, x0.y, x0.z, x0.w, x1.x, x1.y, x1.z, x1.w};
      bf16x8 hh, ll;
#pragma unroll
      for (int j = 0; j < 8; ++j) {
        unsigned short hb = f2bf(xs[j]);
        hh[j] = (short)hb;
        ll[j] = (short)f2bf(xs[j] - bf2f(hb));
      }
      qh[ks] = hh; ql[ks] = ll;
    }
  }

  // staging geometry: chunk c=(r*4+w)*64+lane; row=c>>3; lslot=c&7; gslot=lslot^(row&7)
  int rowA[2], gsA[2];
#pragma unroll
  for (int r = 0; r < 2; ++r) {
    int c = (r * 4 + w) * 64 + lane;
    rowA[r] = c >> 3;
    gsA[r] = (c & 7) ^ ((c >> 3) & 7);
  }
  const unsigned short* Kh_b = Khg + (size_t)bh * S_LEN * D_DIM;
  const unsigned short* Kl_b = Klg + (size_t)bh * S_LEN * D_DIM;
  const unsigned short* Vh_b = Vhg + (size_t)bh * D_DIM * S_LEN;

  auto stage = [&](int buf, int bt) {
#pragma unroll
    for (int r = 0; r < 2; ++r) {
      const int row = rowA[r], gs = gsA[r];
      unsigned short* lbase = &smem[buf][0][0][0] + (r * 4 + w) * 512;  // wave-uniform
      gll16(Kh_b + (size_t)(bt + row) * 64 + gs * 8, lbase);
      gll16(Kl_b + (size_t)(bt + row) * 64 + gs * 8, lbase + 4096);
      gll16(Vh_b + (size_t)row * S_LEN + bt + gs * 8, lbase + 8192);
    }
  };

  f32x16 o[2] = {};
  float lsum = 0.f;
  const int kx = l31 & 7;

  stage(0, 0);
  __syncthreads();

  int cur = 0;
  for (int kt = 0; kt < 32; ++kt) {
    if (kt < 31) stage(cur ^ 1, (kt + 1) * 64);

    bf16x8 pa[4];
#pragma unroll
    for (int kt2 = 0; kt2 < 2; ++kt2) {
      f32x16 acc = {};
      const int krow = kt2 * 32 + l31;
      __builtin_amdgcn_s_setprio(1);
#pragma unroll
      for (int ks = 0; ks < 4; ++ks) {
        const int sl = ((ks * 2 + h) ^ kx) * 8;
        bf16x8 kh = *(const bf16x8*)&smem[cur][0][krow][sl];
        bf16x8 kl = *(const bf16x8*)&smem[cur][1][krow][sl];
        acc = __builtin_amdgcn_mfma_f32_32x32x16_bf16(kh, qh[ks], acc, 0, 0, 0);
        acc = __builtin_amdgcn_mfma_f32_32x32x16_bf16(kh, ql[ks], acc, 0, 0, 0);
        acc = __builtin_amdgcn_mfma_f32_32x32x16_bf16(kl, qh[ks], acc, 0, 0, 0);
      }
      __builtin_amdgcn_s_setprio(0);
      float pr[16];
#pragma unroll
      for (int i = 0; i < 16; ++i) {
        pr[i] = exp2f(acc[i] * 0.18033688011112042f);  // exp(acc/8)
        lsum += pr[i];
      }
      // A-frag = regs in order (V key-axis pre-permuted in transpose):
      // pack adjacent pairs with v_cvt_pk_bf16_f32 (lo=src0, hi=src1)
#pragma unroll
      for (int s2 = 0; s2 < 2; ++s2) {
        u32x4 wds;
#pragma unroll
        for (int p2 = 0; p2 < 4; ++p2) {
          unsigned int pk;
          asm("v_cvt_pk_bf16_f32 %0, %1, %2"
              : "=v"(pk)
              : "v"(pr[s2 * 8 + p2 * 2]), "v"(pr[s2 * 8 + p2 * 2 + 1]));
          wds[p2] = pk;
        }
        pa[kt2 * 2 + s2] = __builtin_bit_cast(bf16x8, wds);
      }
    }

    __builtin_amdgcn_s_setprio(1);
#pragma unroll
    for (int s = 0; s < 4; ++s) {
#pragma unroll
      for (int db = 0; db < 2; ++db) {
        const int vrow = db * 32 + l31;
        const int sl = ((s * 2 + h) ^ kx) * 8;
        bf16x8 vh = *(const bf16x8*)&smem[cur][2][vrow][sl];
        o[db] = __builtin_amdgcn_mfma_f32_32x32x16_bf16(pa[s], vh, o[db], 0, 0, 0);
      }
    }
    __builtin_amdgcn_s_setprio(0);

    __syncthreads();  // drains DMA (vmcnt) for next tile + all waves done with cur
    cur ^= 1;
  }

  // ---- epilogue: l = own-half + partner-half, broadcast 1/l per qrow via LDS ----
  float fl = lsum + __shfl_xor(lsum, 32);
  float inv = 1.0f / fl;
  Lrow[w][l31] = inv;  // both halves write identical value
  __syncthreads();
  float linv[16];
#pragma unroll
  for (int r = 0; r < 16; ++r) linv[r] = Lrow[w][(r & 3) + 8 * (r >> 2) + 4 * h];
  float* ob = out + ((size_t)bh * S_LEN + q0) * D_DIM;
#pragma unroll
  for (int db = 0; db < 2; ++db)
#pragma unroll
    for (int r = 0; r < 16; ++r) {
      const int qr = (r & 3) + 8 * (r >> 2) + 4 * h;
      ob[(size_t)qr * D_DIM + db * 32 + l31] = o[db][r] * linv[r];
    }
}

extern "C" void kernel_launch(void* const* d_in, const int* in_sizes, int n_in,
                              void* d_out, int out_size, void* d_ws, size_t ws_size,
                              hipStream_t stream) {
  const float* q = (const float*)d_in[0];
  const float* k = (const float*)d_in[1];  // [bh][d][s] (pre-transposed)
  const float* v = (const float*)d_in[2];  // [bh][s][d]
  float* out = (float*)d_out;
  unsigned short* ws = (unsigned short*)d_ws;
  unsigned short* Kh = ws;
  unsigned short* Kl = ws + NN;
  unsigned short* Vh = ws + 2 * NN;
  // K: [bh][64][2048] -> Kt [bh][2048][64] hi+lo (straight)
  transpose_split<false, true><<<dim3(32, BH), 256, 0, stream>>>(k, Kh, Kl, 64, 2048);
  // V: [bh][2048][64] -> Vt [bh][64][2048] hi only, key-axis bit2<->bit3 permuted
  transpose_split<true, false><<<dim3(32, BH), 256, 0, stream>>>(v, Vh, nullptr, 2048, 64);
  attn_fused<<<dim3(512), 256, 0, stream>>>(q, Kh, Kl, Vh, out);
}

// Round 6
// 164.325 us; speedup vs baseline: 1.3951x; 1.0443x over previous
//
#include <hip/hip_runtime.h>

#define S_LEN 2048
#define D_DIM 64
#define BH 32
#define NN ((size_t)131072)  // shorts per bh per ws buffer (2048*64)

typedef short bf16x8 __attribute__((ext_vector_type(8)));
typedef float f32x16 __attribute__((ext_vector_type(16)));
typedef unsigned int u32x4 __attribute__((ext_vector_type(4)));

static __device__ __forceinline__ unsigned short f2bf(float x) {
  unsigned int u = __float_as_uint(x);
  u += 0x7fffu + ((u >> 16) & 1u);
  return (unsigned short)(u >> 16);
}
static __device__ __forceinline__ float bf2f(unsigned short h) {
  return __uint_as_float(((unsigned int)h) << 16);
}
static __device__ __forceinline__ void gll16(const void* g, void* l) {
  __builtin_amdgcn_global_load_lds((const __attribute__((address_space(1))) void*)g,
                                   (__attribute__((address_space(3))) void*)l, 16, 0, 0);
}

// K pack: k[bh][d=64][t=2048] fp32 -> Kws{hi,lo}[bh][u=d>>3][t][j=d&7] bf16.
// Each 16B unit = one MFMA A-frag lane slice (t, d-octet) — LDS-linear staging.
__global__ void pack_k(const float* __restrict__ in, unsigned short* __restrict__ oh,
                       unsigned short* __restrict__ ol) {
  __shared__ float tile[64][65];
  const int bh = blockIdx.y, tc = blockIdx.x, tid = threadIdx.x;
  const float* src = in + (size_t)bh * 64 * 2048;
  const int c4 = (tid & 15) * 4, r0 = tid >> 4;
#pragma unroll
  for (int rep = 0; rep < 4; ++rep) {
    int r = r0 + rep * 16;  // r = d
    float4 x = *(const float4*)&src[(size_t)r * 2048 + tc * 64 + c4];
    tile[r][c4] = x.x; tile[r][c4 + 1] = x.y; tile[r][c4 + 2] = x.z; tile[r][c4 + 3] = x.w;
  }
  __syncthreads();
  oh += (size_t)bh * NN; ol += (size_t)bh * NN;
#pragma unroll
  for (int rep = 0; rep < 2; ++rep) {
    int unit = rep * 256 + tid;
    int u = unit >> 6, t = unit & 63;
    alignas(16) unsigned short hbuf[8];
    alignas(16) unsigned short lbuf[8];
#pragma unroll
    for (int j = 0; j < 8; ++j) {
      float x = tile[u * 8 + j][t];
      unsigned short hb = f2bf(x);
      hbuf[j] = hb;
      lbuf[j] = f2bf(x - bf2f(hb));
    }
    size_t o = ((size_t)u * 2048 + tc * 64 + t) * 8;
    *(int4*)&oh[o] = *(const int4*)hbuf;
    *(int4*)&ol[o] = *(const int4*)lbuf;
  }
}

// V pack: v[bh][t=2048][d=64] fp32 -> Vws[bh][thi=(tile*8+s*2+h)][d][8 tj] bf16 (hi only).
// Key order inside each 16B unit matches the PV A-fragment register order:
// key = s*16 + h*4 + (j&3) + 8*(j>>2).
__global__ void pack_v(const float* __restrict__ in, unsigned short* __restrict__ oh) {
  __shared__ float tile[64][65];
  const int bh = blockIdx.y, tr = blockIdx.x, tid = threadIdx.x;
  const float* src = in + (size_t)bh * 2048 * 64;
  const int c4 = (tid & 15) * 4, r0 = tid >> 4;
#pragma unroll
  for (int rep = 0; rep < 4; ++rep) {
    int r = r0 + rep * 16;  // r = t_in
    float4 x = *(const float4*)&src[(size_t)(tr * 64 + r) * 64 + c4];
    tile[r][c4] = x.x; tile[r][c4 + 1] = x.y; tile[r][c4 + 2] = x.z; tile[r][c4 + 3] = x.w;
  }
  __syncthreads();
  oh += (size_t)bh * NN;
#pragma unroll
  for (int rep = 0; rep < 2; ++rep) {
    int unit = rep * 256 + tid;
    int u = unit >> 6, d = unit & 63;  // u = s*2 + h
    alignas(16) unsigned short hbuf[8];
#pragma unroll
    for (int j = 0; j < 8; ++j) {
      int t_loc = (u >> 1) * 16 + (u & 1) * 4 + (j & 3) + 8 * (j >> 2);
      hbuf[j] = f2bf(tile[t_loc][d]);
    }
    size_t o = ((size_t)(tr * 8 + u) * 64 + d) * 8;
    *(int4*)&oh[o] = *(const int4*)hbuf;
  }
}

// Fused exp-attention. 512 thr = 8 waves = 4 q-tiles x 2 key-halves (split-K).
// Swapped-QK^T 32x32x16, in-register P, hi/lo bf16 QK, bf16 V.
// Fragment-linear LDS: every ds_read_b128 = chunk_base + lane*16 (0 conflicts).
__global__ __launch_bounds__(512, 4) void attn_fused(
    const float* __restrict__ q, const unsigned short* __restrict__ Khg,
    const unsigned short* __restrict__ Klg, const unsigned short* __restrict__ Vhg,
    float* __restrict__ out) {
  __shared__ __align__(16) unsigned short smem[2][12288];  // 2 x 24KB: [Kh 8K][Kl 8K][Vh 8K]

  const int bid = blockIdx.x;
  const int swz = (bid & 7) * 64 + (bid >> 3);  // XCD-contiguous: same bh clusters per XCD
  const int bh = swz >> 4;
  const int qt = swz & 15;
  const int tid = threadIdx.x;
  const int w = tid >> 6;
  const int lane = tid & 63;
  const int l31 = lane & 31;
  const int h = lane >> 5;
  const int qtile = w >> 1;   // 0..3
  const int kh2 = w & 1;      // key-half 0/1

  // ---- Q B-fragments: col(q)=l31, k(d)=ks*16+h*8+j ----
  bf16x8 qh[4], ql[4];
  {
    const float* qb = q + ((size_t)bh * S_LEN + qt * 128 + qtile * 32 + l31) * 64;
#pragma unroll
    for (int ks = 0; ks < 4; ++ks) {
      const float* p = qb + ks * 16 + h * 8;
      float4 x0 = *(const float4*)p;
      float4 x1 = *(const float4*)(p + 4);
      float xs[8] = {x0.x, x0.y, x0.z, x0.w, x1.x, x1.y, x1.z, x1.w};
      bf16x8 hh, ll;
#pragma unroll
      for (int j = 0; j < 8; ++j) {
        unsigned short hb = f2bf(xs[j]);
        hh[j] = (short)hb;
        ll[j] = (short)f2bf(xs[j] - bf2f(hb));
      }
      qh[ks] = hh; ql[ks] = ll;
    }
  }

  // ---- staging: 24 chunks of 1KB per tile, 3 per wave ----
  const unsigned short* srcp[3];
  int stp[3], ldso[3];
#pragma unroll
  for (int i = 0; i < 3; ++i) {
    int g = w * 3 + i;
    int c = g & 7, typ = g >> 3;  // 0:Kh 1:Kl 2:Vh
    if (typ < 2) {
      size_t off = ((size_t)((c >> 1) * 2 + h) * 2048 + (c & 1) * 32 + l31) * 8;
      srcp[i] = (typ == 0 ? Khg : Klg) + (size_t)bh * NN + off;
      stp[i] = 512;                    // +64 keys per tile
      ldso[i] = typ * 4096 + c * 512;  // shorts
    } else {
      size_t off = ((size_t)((c >> 1) * 2 + h) * 64 + (c & 1) * 32 + l31) * 8;
      srcp[i] = Vhg + (size_t)bh * NN + off;
      stp[i] = 4096;                   // +8 t-octets per tile
      ldso[i] = 8192 + c * 512;
    }
  }
  auto stage = [&](int buf, int tile) {
#pragma unroll
    for (int i = 0; i < 3; ++i)
      gll16(srcp[i] + (size_t)tile * stp[i], &smem[buf][ldso[i]]);
  };

  f32x16 o2[2] = {};
  float lsum = 0.f;
  const char* lp = (const char*)&smem[0][0] + lane * 16;

  stage(0, 0);
  __syncthreads();

  auto body = [&](int kt, int buf) {
    if (kt < 31) stage(buf ^ 1, kt + 1);
    const char* B = lp + buf * 24576;
    // ---- QK^T (A=K rows its khalf, B=Q) ----
    f32x16 acc = {};
    __builtin_amdgcn_s_setprio(1);
#pragma unroll
    for (int ks = 0; ks < 4; ++ks) {
      bf16x8 kh = *(const bf16x8*)(B + (ks * 2 + kh2) * 1024);
      bf16x8 kl = *(const bf16x8*)(B + 8192 + (ks * 2 + kh2) * 1024);
      acc = __builtin_amdgcn_mfma_f32_32x32x16_bf16(kh, qh[ks], acc, 0, 0, 0);
      acc = __builtin_amdgcn_mfma_f32_32x32x16_bf16(kh, ql[ks], acc, 0, 0, 0);
      acc = __builtin_amdgcn_mfma_f32_32x32x16_bf16(kl, qh[ks], acc, 0, 0, 0);
    }
    __builtin_amdgcn_s_setprio(0);
    // ---- exp + pack P (A-frag register order; V key axis pre-permuted) ----
    float pr[16];
#pragma unroll
    for (int i = 0; i < 16; ++i) {
      pr[i] = exp2f(acc[i] * 0.18033688011112042f);  // exp(acc/8)
      lsum += pr[i];
    }
    bf16x8 pa[2];
#pragma unroll
    for (int s2 = 0; s2 < 2; ++s2) {
      u32x4 wds;
#pragma unroll
      for (int p2 = 0; p2 < 4; ++p2) {
        unsigned int pk;
        asm("v_cvt_pk_bf16_f32 %0, %1, %2"
            : "=v"(pk)
            : "v"(pr[s2 * 8 + p2 * 2]), "v"(pr[s2 * 8 + p2 * 2 + 1]));
        wds[p2] = pk;
      }
      pa[s2] = __builtin_bit_cast(bf16x8, wds);
    }
    // ---- O += P.V ----
    __builtin_amdgcn_s_setprio(1);
#pragma unroll
    for (int db = 0; db < 2; ++db) {
      bf16x8 v0 = *(const bf16x8*)(B + 16384 + ((kh2 * 2 + 0) * 2 + db) * 1024);
      bf16x8 v1 = *(const bf16x8*)(B + 16384 + ((kh2 * 2 + 1) * 2 + db) * 1024);
      o2[db] = __builtin_amdgcn_mfma_f32_32x32x16_bf16(pa[0], v0, o2[db], 0, 0, 0);
      o2[db] = __builtin_amdgcn_mfma_f32_32x32x16_bf16(pa[1], v1, o2[db], 0, 0, 0);
    }
    __builtin_amdgcn_s_setprio(0);
    __syncthreads();  // drains DMA for next tile; all waves done with buf
  };

  for (int kt = 0; kt < 32; kt += 2) {
    body(kt, 0);
    body(kt + 1, 1);
  }

  // ---- epilogue: combine key-halves, normalize, store ----
  float ls = lsum + __shfl_xor(lsum, 32);  // h-pair: full 32-key half-sum per q=l31
  float* sc = (float*)&smem[0][0];
  if (kh2 == 1) {
#pragma unroll
    for (int db = 0; db < 2; ++db)
#pragma unroll
      for (int r = 0; r < 16; ++r)
        sc[(qtile * 2 + db) * 1024 + (h * 16 + r) * 32 + l31] = o2[db][r];
    sc[8192 + qtile * 32 + l31] = ls;
  }
  __syncthreads();
  if (kh2 == 1) return;
  float ltot = ls + sc[8192 + qtile * 32 + l31];
  float inv = 1.0f / ltot;
  sc[8320 + qtile * 32 + l31] = inv;  // broadcast q-indexed -> row-indexed
  asm volatile("s_waitcnt lgkmcnt(0)" ::: "memory");
  float* ob = out + ((size_t)bh * S_LEN + qt * 128 + qtile * 32) * 64;
#pragma unroll
  for (int r = 0; r < 16; ++r) {
    const int qr = (r & 3) + 8 * (r >> 2) + 4 * h;
    float iv = sc[8320 + qtile * 32 + qr];
#pragma unroll
    for (int db = 0; db < 2; ++db) {
      float val = (o2[db][r] + sc[(qtile * 2 + db) * 1024 + (h * 16 + r) * 32 + l31]) * iv;
      ob[(size_t)qr * 64 + db * 32 + l31] = val;
    }
  }
}

extern "C" void kernel_launch(void* const* d_in, const int* in_sizes, int n_in,
                              void* d_out, int out_size, void* d_ws, size_t ws_size,
                              hipStream_t stream) {
  const float* q = (const float*)d_in[0];
  const float* k = (const float*)d_in[1];  // [bh][d][s] (pre-transposed)
  const float* v = (const float*)d_in[2];  // [bh][s][d]
  float* out = (float*)d_out;
  unsigned short* ws = (unsigned short*)d_ws;
  unsigned short* Kh = ws;
  unsigned short* Kl = ws + BH * NN;
  unsigned short* Vh = ws + 2 * BH * NN;
  pack_k<<<dim3(32, BH), 256, 0, stream>>>(k, Kh, Kl);
  pack_v<<<dim3(32, BH), 256, 0, stream>>>(v, Vh);
  attn_fused<<<dim3(512), 512, 0, stream>>>(q, Kh, Kl, Vh, out);
}

// Round 7
// 161.586 us; speedup vs baseline: 1.4187x; 1.0169x over previous
//
#include <hip/hip_runtime.h>

#define S_LEN 2048
#define D_DIM 64
#define BH 32
#define NN ((size_t)131072)  // shorts per bh per ws buffer (2048*64)

typedef short bf16x8 __attribute__((ext_vector_type(8)));
typedef float f32x16 __attribute__((ext_vector_type(16)));
typedef unsigned int u32x4 __attribute__((ext_vector_type(4)));

static __device__ __forceinline__ unsigned short f2bf(float x) {
  unsigned int u = __float_as_uint(x);
  u += 0x7fffu + ((u >> 16) & 1u);
  return (unsigned short)(u >> 16);
}
static __device__ __forceinline__ float bf2f(unsigned short h) {
  return __uint_as_float(((unsigned int)h) << 16);
}
static __device__ __forceinline__ void gll16(const void* g, void* l) {
  __builtin_amdgcn_global_load_lds((const __attribute__((address_space(1))) void*)g,
                                   (__attribute__((address_space(3))) void*)l, 16, 0, 0);
}

// Fused pre-pass, barrier-free / LDS-free. One thread = one 16B fragment unit.
//   K region (gid < 524288): unit (bh, u=d-octet, t). Reads K[bh][u*8+j][t]
//     (stride 8KB, lanes along t -> 256B coalesced per j), writes Kh/Kl
//     [bh][u][t][j] = hi/lo bf16 split.
//   V region: unit (bh, thi, d). Reads V[bh][t_perm(thi,j)][d] (stride 256B,
//     lanes along d -> 256B coalesced per j), writes Vh[bh][thi][d][j], with
//     the PV A-fragment key permutation t_loc = (u>>1)*16+(u&1)*4+(j&3)+8*(j>>2).
__global__ __launch_bounds__(256) void pack_all(
    const float* __restrict__ kin, const float* __restrict__ vin,
    unsigned short* __restrict__ Kh, unsigned short* __restrict__ Kl,
    unsigned short* __restrict__ Vh) {
  const int gid = blockIdx.x * 256 + threadIdx.x;
  if (gid < 524288) {  // ---- K: 32 bh x 8 u x 2048 t ----
    const int bh = gid >> 14, rem = gid & 16383;
    const int u = rem >> 11, t = rem & 2047;
    const float* src = kin + (size_t)bh * 131072 + (size_t)(u * 8) * 2048 + t;
    float x[8];
#pragma unroll
    for (int j = 0; j < 8; ++j) x[j] = src[j * 2048];
    u32x4 hv, lv;
#pragma unroll
    for (int p = 0; p < 4; ++p) {
      unsigned int pk;
      asm("v_cvt_pk_bf16_f32 %0, %1, %2" : "=v"(pk) : "v"(x[2 * p]), "v"(x[2 * p + 1]));
      float l0 = x[2 * p] - __uint_as_float(pk << 16);
      float l1 = x[2 * p + 1] - __uint_as_float(pk & 0xffff0000u);
      unsigned int pl;
      asm("v_cvt_pk_bf16_f32 %0, %1, %2" : "=v"(pl) : "v"(l0), "v"(l1));
      hv[p] = pk;
      lv[p] = pl;
    }
    const size_t o = (size_t)bh * NN + (size_t)(u * 2048 + t) * 8;
    *(u32x4*)(Kh + o) = hv;
    *(u32x4*)(Kl + o) = lv;
  } else {  // ---- V: 32 bh x 256 thi x 64 d ----
    const int g2 = gid - 524288;
    const int bh = g2 >> 14, rem = g2 & 16383;
    const int thi = rem >> 6, d = rem & 63;
    const int tr = thi >> 3, u = thi & 7;
    const float* src = vin + (size_t)bh * 131072 + d;
    float x[8];
#pragma unroll
    for (int j = 0; j < 8; ++j) {
      int t = tr * 64 + (u >> 1) * 16 + (u & 1) * 4 + (j & 3) + 8 * (j >> 2);
      x[j] = src[(size_t)t * 64];
    }
    u32x4 hv;
#pragma unroll
    for (int p = 0; p < 4; ++p) {
      unsigned int pk;
      asm("v_cvt_pk_bf16_f32 %0, %1, %2" : "=v"(pk) : "v"(x[2 * p]), "v"(x[2 * p + 1]));
      hv[p] = pk;
    }
    *(u32x4*)(Vh + (size_t)bh * NN + (size_t)(thi * 64 + d) * 8) = hv;
  }
}

// Fused exp-attention. 512 thr = 8 waves = 4 q-tiles x 2 key-halves (split-K).
// Swapped-QK^T 32x32x16, in-register P, hi/lo bf16 QK, bf16 V.
// Fragment-linear LDS: every ds_read_b128 = chunk_base + lane*16 (0 conflicts).
__global__ __launch_bounds__(512, 4) void attn_fused(
    const float* __restrict__ q, const unsigned short* __restrict__ Khg,
    const unsigned short* __restrict__ Klg, const unsigned short* __restrict__ Vhg,
    float* __restrict__ out) {
  __shared__ __align__(16) unsigned short smem[2][12288];  // 2 x 24KB: [Kh 8K][Kl 8K][Vh 8K]

  const int bid = blockIdx.x;
  const int swz = (bid & 7) * 64 + (bid >> 3);  // XCD-contiguous: same bh clusters per XCD
  const int bh = swz >> 4;
  const int qt = swz & 15;
  const int tid = threadIdx.x;
  const int w = tid >> 6;
  const int lane = tid & 63;
  const int l31 = lane & 31;
  const int h = lane >> 5;
  const int qtile = w >> 1;   // 0..3
  const int kh2 = w & 1;      // key-half 0/1

  // ---- Q B-fragments: col(q)=l31, k(d)=ks*16+h*8+j ----
  bf16x8 qh[4], ql[4];
  {
    const float* qb = q + ((size_t)bh * S_LEN + qt * 128 + qtile * 32 + l31) * 64;
#pragma unroll
    for (int ks = 0; ks < 4; ++ks) {
      const float* p = qb + ks * 16 + h * 8;
      float4 x0 = *(const float4*)p;
      float4 x1 = *(const float4*)(p + 4);
      float xs[8] = {x0.x, x0.y, x0.z, x0.w, x1.x, x1.y, x1.z, x1.w};
      bf16x8 hh, ll;
#pragma unroll
      for (int j = 0; j < 8; ++j) {
        unsigned short hb = f2bf(xs[j]);
        hh[j] = (short)hb;
        ll[j] = (short)f2bf(xs[j] - bf2f(hb));
      }
      qh[ks] = hh; ql[ks] = ll;
    }
  }

  // ---- staging: 24 chunks of 1KB per tile, 3 per wave ----
  const unsigned short* srcp[3];
  int stp[3], ldso[3];
#pragma unroll
  for (int i = 0; i < 3; ++i) {
    int g = w * 3 + i;
    int c = g & 7, typ = g >> 3;  // 0:Kh 1:Kl 2:Vh
    if (typ < 2) {
      size_t off = ((size_t)((c >> 1) * 2 + h) * 2048 + (c & 1) * 32 + l31) * 8;
      srcp[i] = (typ == 0 ? Khg : Klg) + (size_t)bh * NN + off;
      stp[i] = 512;                    // +64 keys per tile
      ldso[i] = typ * 4096 + c * 512;  // shorts
    } else {
      size_t off = ((size_t)((c >> 1) * 2 + h) * 64 + (c & 1) * 32 + l31) * 8;
      srcp[i] = Vhg + (size_t)bh * NN + off;
      stp[i] = 4096;                   // +8 t-octets per tile
      ldso[i] = 8192 + c * 512;
    }
  }
  auto stage = [&](int buf, int tile) {
#pragma unroll
    for (int i = 0; i < 3; ++i)
      gll16(srcp[i] + (size_t)tile * stp[i], &smem[buf][ldso[i]]);
  };

  f32x16 o2[2] = {};
  float lsum = 0.f;
  const char* lp = (const char*)&smem[0][0] + lane * 16;

  stage(0, 0);
  __syncthreads();

  auto body = [&](int kt, int buf) {
    if (kt < 31) stage(buf ^ 1, kt + 1);
    const char* B = lp + buf * 24576;
    // ---- QK^T (A=K rows its khalf, B=Q) ----
    f32x16 acc = {};
    __builtin_amdgcn_s_setprio(1);
#pragma unroll
    for (int ks = 0; ks < 4; ++ks) {
      bf16x8 kh = *(const bf16x8*)(B + (ks * 2 + kh2) * 1024);
      bf16x8 kl = *(const bf16x8*)(B + 8192 + (ks * 2 + kh2) * 1024);
      acc = __builtin_amdgcn_mfma_f32_32x32x16_bf16(kh, qh[ks], acc, 0, 0, 0);
      acc = __builtin_amdgcn_mfma_f32_32x32x16_bf16(kh, ql[ks], acc, 0, 0, 0);
      acc = __builtin_amdgcn_mfma_f32_32x32x16_bf16(kl, qh[ks], acc, 0, 0, 0);
    }
    __builtin_amdgcn_s_setprio(0);
    // ---- exp + pack P (A-frag register order; V key axis pre-permuted) ----
    float pr[16];
#pragma unroll
    for (int i = 0; i < 16; ++i) {
      pr[i] = exp2f(acc[i] * 0.18033688011112042f);  // exp(acc/8)
      lsum += pr[i];
    }
    bf16x8 pa[2];
#pragma unroll
    for (int s2 = 0; s2 < 2; ++s2) {
      u32x4 wds;
#pragma unroll
      for (int p2 = 0; p2 < 4; ++p2) {
        unsigned int pk;
        asm("v_cvt_pk_bf16_f32 %0, %1, %2"
            : "=v"(pk)
            : "v"(pr[s2 * 8 + p2 * 2]), "v"(pr[s2 * 8 + p2 * 2 + 1]));
        wds[p2] = pk;
      }
      pa[s2] = __builtin_bit_cast(bf16x8, wds);
    }
    // ---- O += P.V ----
    __builtin_amdgcn_s_setprio(1);
#pragma unroll
    for (int db = 0; db < 2; ++db) {
      bf16x8 v0 = *(const bf16x8*)(B + 16384 + ((kh2 * 2 + 0) * 2 + db) * 1024);
      bf16x8 v1 = *(const bf16x8*)(B + 16384 + ((kh2 * 2 + 1) * 2 + db) * 1024);
      o2[db] = __builtin_amdgcn_mfma_f32_32x32x16_bf16(pa[0], v0, o2[db], 0, 0, 0);
      o2[db] = __builtin_amdgcn_mfma_f32_32x32x16_bf16(pa[1], v1, o2[db], 0, 0, 0);
    }
    __builtin_amdgcn_s_setprio(0);
    __syncthreads();  // drains DMA for next tile; all waves done with buf
  };

  for (int kt = 0; kt < 32; kt += 2) {
    body(kt, 0);
    body(kt + 1, 1);
  }

  // ---- epilogue: combine key-halves, normalize, store ----
  float ls = lsum + __shfl_xor(lsum, 32);  // h-pair: full 32-key half-sum per q=l31
  float* sc = (float*)&smem[0][0];
  if (kh2 == 1) {
#pragma unroll
    for (int db = 0; db < 2; ++db)
#pragma unroll
      for (int r = 0; r < 16; ++r)
        sc[(qtile * 2 + db) * 1024 + (h * 16 + r) * 32 + l31] = o2[db][r];
    sc[8192 + qtile * 32 + l31] = ls;
  }
  __syncthreads();
  if (kh2 == 1) return;
  float ltot = ls + sc[8192 + qtile * 32 + l31];
  float inv = 1.0f / ltot;
  sc[8320 + qtile * 32 + l31] = inv;  // broadcast q-indexed -> row-indexed
  asm volatile("s_waitcnt lgkmcnt(0)" ::: "memory");
  float* ob = out + ((size_t)bh * S_LEN + qt * 128 + qtile * 32) * 64;
#pragma unroll
  for (int r = 0; r < 16; ++r) {
    const int qr = (r & 3) + 8 * (r >> 2) + 4 * h;
    float iv = sc[8320 + qtile * 32 + qr];
#pragma unroll
    for (int db = 0; db < 2; ++db) {
      float val = (o2[db][r] + sc[(qtile * 2 + db) * 1024 + (h * 16 + r) * 32 + l31]) * iv;
      ob[(size_t)qr * 64 + db * 32 + l31] = val;
    }
  }
}

extern "C" void kernel_launch(void* const* d_in, const int* in_sizes, int n_in,
                              void* d_out, int out_size, void* d_ws, size_t ws_size,
                              hipStream_t stream) {
  const float* q = (const float*)d_in[0];
  const float* k = (const float*)d_in[1];  // [bh][d][s] (pre-transposed)
  const float* v = (const float*)d_in[2];  // [bh][s][d]
  float* out = (float*)d_out;
  unsigned short* ws = (unsigned short*)d_ws;
  unsigned short* Kh = ws;
  unsigned short* Kl = ws + BH * NN;
  unsigned short* Vh = ws + 2 * BH * NN;
  pack_all<<<dim3(4096), 256, 0, stream>>>(k, v, Kh, Kl, Vh);
  attn_fused<<<dim3(512), 512, 0, stream>>>(q, Kh, Kl, Vh, out);
}